// Round 7
// baseline (578.399 us; speedup 1.0000x reference)
//
#include <hip/hip_runtime.h>
#include <stdint.h>

#define K_DIM 4096
#define M_TOK 8192
#define N_OUT 4096

typedef int v4i __attribute__((ext_vector_type(4)));
typedef int v16i __attribute__((ext_vector_type(16)));

// ---- workspace layout (bytes) ----
// q       : int8 [8192][4096]   @ 0          (33554432)
// tw      : int8 [4096][4096]   @ 33554432   (16777216)
// rs      : float[8192]         @ 50331648   (32768)
// partial : double[1024]        @ 50364416   (8192)
// meanp   : float               @ 50372608   (4)

#define BAR()                                     \
    do {                                          \
        asm volatile("" ::: "memory");            \
        __builtin_amdgcn_s_barrier();             \
        asm volatile("" ::: "memory");            \
    } while (0)

__device__ __forceinline__ void gload_lds16(const void* g, void* l) {
    auto gp = reinterpret_cast<const __attribute__((address_space(1))) uint32_t*>(
        reinterpret_cast<uintptr_t>(g));
    auto lp = reinterpret_cast<__attribute__((address_space(3))) uint32_t*>(
        reinterpret_cast<uintptr_t>(l));
    __builtin_amdgcn_global_load_lds(gp, lp, 16, 0, 0);
}

// --- per-token activation quantization: one token per WAVE (no LDS, no
// __syncthreads, butterfly shfl_xor max). 2048 blocks x 4 waves. ---
__global__ __launch_bounds__(256) void quant_act(const float* __restrict__ x,
                                                 int8_t* __restrict__ q,
                                                 float* __restrict__ rs) {
    const int token = blockIdx.x * 4 + (threadIdx.x >> 6);
    const int lane = threadIdx.x & 63;
    const float4* x4 = (const float4*)(x + (size_t)token * K_DIM);
    float4 v[16];
    float m = 0.0f;
#pragma unroll
    for (int r = 0; r < 16; ++r) {
        v[r] = x4[lane + 64 * r];
        m = fmaxf(m, fmaxf(fmaxf(fabsf(v[r].x), fabsf(v[r].y)),
                           fmaxf(fabsf(v[r].z), fabsf(v[r].w))));
    }
#pragma unroll
    for (int off = 32; off; off >>= 1) m = fmaxf(m, __shfl_xor(m, off, 64));
    const float s = 127.0f / fmaxf(m, 1e-5f);
    char4* q4 = (char4*)(q + (size_t)token * K_DIM);
#pragma unroll
    for (int r = 0; r < 16; ++r) {
        float4 f = v[r];
        char4 c;
        c.x = (signed char)fminf(fmaxf(rintf(f.x * s), -128.0f), 127.0f);
        c.y = (signed char)fminf(fmaxf(rintf(f.y * s), -128.0f), 127.0f);
        c.z = (signed char)fminf(fmaxf(rintf(f.z * s), -128.0f), 127.0f);
        c.w = (signed char)fminf(fmaxf(rintf(f.w * s), -128.0f), 127.0f);
        q4[lane + 64 * r] = c;
    }
    if (lane == 0) rs[token] = 1.0f / s;
}

// --- sum |w| partials: 1024 blocks, NO atomics (per-block partial to global) ---
__global__ __launch_bounds__(256) void wabs_sum(const float* __restrict__ w,
                                                double* __restrict__ partial) {
    const size_t n4 = (size_t)N_OUT * K_DIM / 4;
    const size_t stride = (size_t)gridDim.x * 256;
    const float4* w4 = (const float4*)w;
    float sum = 0.0f;
    for (size_t j = (size_t)blockIdx.x * 256 + threadIdx.x; j < n4; j += stride) {
        float4 f = w4[j];
        sum += fabsf(f.x) + fabsf(f.y) + fabsf(f.z) + fabsf(f.w);
    }
    double d = (double)sum;
#pragma unroll
    for (int off = 32; off; off >>= 1) d += __shfl_down(d, off, 64);
    __shared__ double wsum[4];
    const int t = threadIdx.x;
    if ((t & 63) == 0) wsum[t >> 6] = d;
    __syncthreads();
    if (t == 0) partial[blockIdx.x] = wsum[0] + wsum[1] + wsum[2] + wsum[3];
}

// --- ternarize: every block sums the 1024 partials (identical deterministic
// order -> identical mean), then tw = clip(round(w*sw),-1,1). Block 0 also
// publishes clamped mean (float) for the GEMM epilogue. 4 float4/thread. ---
__global__ __launch_bounds__(256) void ternarize(const float* __restrict__ w,
                                                 int8_t* __restrict__ tw,
                                                 const double* __restrict__ partial,
                                                 float* __restrict__ meanp) {
    const int t = threadIdx.x;
    double d = partial[t] + partial[t + 256] + partial[t + 512] + partial[t + 768];
#pragma unroll
    for (int off = 32; off; off >>= 1) d += __shfl_down(d, off, 64);
    __shared__ double pr[4];
    if ((t & 63) == 0) pr[t >> 6] = d;
    __syncthreads();
    const double tot = pr[0] + pr[1] + pr[2] + pr[3];
    const float mean = fmaxf((float)(tot * (1.0 / ((double)N_OUT * (double)K_DIM))), 1e-5f);
    const float sw = 1.0f / mean;
    if (blockIdx.x == 0 && t == 0) *meanp = mean;
    const float4* w4 = (const float4*)w;
    char4* t4 = (char4*)tw;
    const size_t base = (size_t)blockIdx.x * 1024 + t;
#pragma unroll
    for (int r = 0; r < 4; ++r) {
        float4 f = w4[base + r * 256];
        char4 c;
        c.x = (signed char)fminf(fmaxf(rintf(f.x * sw), -1.0f), 1.0f);
        c.y = (signed char)fminf(fmaxf(rintf(f.y * sw), -1.0f), 1.0f);
        c.z = (signed char)fminf(fmaxf(rintf(f.z * sw), -1.0f), 1.0f);
        c.w = (signed char)fminf(fmaxf(rintf(f.w * sw), -1.0f), 1.0f);
        t4[base + r * 256] = c;
    }
}

// --- i8 GEMM: 256x256 block, 4 waves (256 thr), wave tile 128x128 ---
// Rationale (round-5): at 64x128 wave tiles the LDS-read pipe (~0.75 KB/MFMA,
// ~12 cyc/KB) is at parity with the MFMA pipe (9.2 cyc) -> lgkmcnt stalls cap
// MfmaUtil ~42%. 128x128 wave tile: 8 frag reads per 32 MFMA = 0.5 KB/MFMA ->
// LDS ~65% of MFMA load. Cost: acc 4x4x16 = 256 AGPR -> 1 wave/SIMD; the 16
// independent MFMAs per cluster (~586 cyc pipe occupancy) cover the wave's own
// 8 ds_read + 8 gload issue, and all operands are read >=1 cluster ahead.
// LDS: 4-slot ring (32 KB/slot). Stage tile t+3 at tile t into slot (t-1)&3
// (reads of it ended before the barrier that opened tile t -> race-free).
// vmcnt: 8 loads/thread/tile, depth-3 in flight -> vmcnt(16) steady state,
// drain 16->8->0 at t=61/62. One barrier per tile.
// Swizzle: 16-B chunk c of row r stored at c ^ (r&3) ^ ((r>>2)&3), source
// column pre-swizzled; invariant under row+64k. Verified conflict-free (r3: 0).
__global__ __launch_bounds__(256, 1) void gemm_i8(const int8_t* __restrict__ A,
                                                  const int8_t* __restrict__ B,
                                                  const float* __restrict__ rs,
                                                  const float* __restrict__ meanp,
                                                  float* __restrict__ out) {
    // T1: bijective XCD swizzle (512 wgs, 8 XCDs, 64 contiguous wgs per XCD)
    const int nwgx = N_OUT / 256;  // 16
    const int orig = blockIdx.y * nwgx + blockIdx.x;
    const int wg = (orig & 7) * 64 + (orig >> 3);
    const int bm = (wg / nwgx) * 256;
    const int bn = (wg % nwgx) * 256;

    __shared__ int8_t smem[4][2][16384];  // [slot][A,B][256 rows x 64 B]

    const int t0 = threadIdx.x;
    const int lane = t0 & 63;
    const int wave = t0 >> 6;
    const int wm = (wave >> 1) * 128;   // 0,128
    const int wn = (wave & 1) * 128;    // 0,128

    v16i accv[4][4] = {};

    // staging: thread t0 -> row R = (t0>>2) + 64*round, chunk t0&3 of that row;
    // source chunk (t0&3)^(R&3)^((R>>2)&3); both XOR terms invariant under
    // R += 64 -> one scol for all rounds.
    const int R0 = t0 >> 2;
    const int scol = (((t0 & 3) ^ (R0 & 3) ^ ((R0 >> 2) & 3)) << 4);
    const int8_t* Ag = A + (size_t)(bm + R0) * K_DIM + scol;
    const int8_t* Bg = B + (size_t)(bn + R0) * K_DIM + scol;
    int8_t* ldst = &smem[0][0][0] + (size_t)t0 * 16;  // 256 thr x 16 B = 4 KB/round

    // fragment read constants (A/B row = lane&31, 16B chunk = ks*2 + (lane>>5))
    const int l31 = lane & 31;
    const int lh = lane >> 5;
    const int sx = (l31 & 3) ^ ((l31 >> 2) & 3);
    const int co0 = ((lh ^ sx) << 4);        // ks=0 chunk byte offset
    const int co1 = (((2 + lh) ^ sx) << 4);  // ks=1 chunk byte offset
    int offA[4], offB[4];
#pragma unroll
    for (int i = 0; i < 4; ++i) {
        offA[i] = (wm + i * 32 + l31) * 64;
        offB[i] = (wn + i * 32 + l31) * 64;
    }

#define STAGE(tile, sb)                                                       \
    do {                                                                      \
        const int k0_ = (tile) * 64;                                          \
        _Pragma("unroll")                                                     \
        for (int r_ = 0; r_ < 4; ++r_) {                                      \
            gload_lds16(Ag + k0_ + (size_t)(64 * r_) * K_DIM, (sb) + r_ * 4096);          \
            gload_lds16(Bg + k0_ + (size_t)(64 * r_) * K_DIM, (sb) + 16384 + r_ * 4096);  \
        }                                                                     \
    } while (0)

    // prologue: stage tiles 0..2 into slots 0..2 (24 loads/thread)
#pragma unroll
    for (int pt = 0; pt < 3; ++pt) STAGE(pt, ldst + pt * 32768);
    asm volatile("s_waitcnt vmcnt(16)" ::: "memory");  // tile 0 resident
    BAR();

    v4i ca[4], cb[4];  // ks0 frags (loaded one half-tile ahead)
    {
        const int8_t* aB = &smem[0][0][0];
        const int8_t* bB = &smem[0][1][0];
#pragma unroll
        for (int i = 0; i < 4; ++i) {
            ca[i] = *(const v4i*)(aB + offA[i] + co0);
            cb[i] = *(const v4i*)(bB + offB[i] + co0);
        }
    }

#pragma unroll 1
    for (int t = 0; t < 64; ++t) {
        const int slot = t & 3;
        const int8_t* aB = &smem[slot][0][0];
        const int8_t* bB = &smem[slot][1][0];

        // stage tile t+3 into slot (t+3)&3 == (t-1)&3
        if (t < 61) STAGE(t + 3, ldst + ((t + 3) & 3) * 32768);

        // ks1 frags of tile t (consumed after the barrier)
        v4i na[4], nb[4];
#pragma unroll
        for (int i = 0; i < 4; ++i) {
            na[i] = *(const v4i*)(aB + offA[i] + co1);
            nb[i] = *(const v4i*)(bB + offB[i] + co1);
        }

        __builtin_amdgcn_s_setprio(1);
#pragma unroll
        for (int m = 0; m < 4; ++m)
#pragma unroll
            for (int n = 0; n < 4; ++n)
                accv[m][n] = __builtin_amdgcn_mfma_i32_32x32x32_i8(ca[m], cb[n], accv[m][n], 0, 0, 0);
        __builtin_amdgcn_s_setprio(0);

        // next tile resident; never vmcnt(0) in steady state
        if (t < 61) asm volatile("s_waitcnt vmcnt(16)" ::: "memory");
        else if (t == 61) asm volatile("s_waitcnt vmcnt(8)" ::: "memory");
        else if (t == 62) asm volatile("s_waitcnt vmcnt(0)" ::: "memory");
        if (t < 63) {
            BAR();
            // ks0 frags of tile t+1 (consumed next iteration)
            const int nslot = (t + 1) & 3;
            const int8_t* aN = &smem[nslot][0][0];
            const int8_t* bN = &smem[nslot][1][0];
#pragma unroll
            for (int i = 0; i < 4; ++i) {
                ca[i] = *(const v4i*)(aN + offA[i] + co0);
                cb[i] = *(const v4i*)(bN + offB[i] + co0);
            }
        }

        __builtin_amdgcn_s_setprio(1);
#pragma unroll
        for (int m = 0; m < 4; ++m)
#pragma unroll
            for (int n = 0; n < 4; ++n)
                accv[m][n] = __builtin_amdgcn_mfma_i32_32x32x32_i8(na[m], nb[n], accv[m][n], 0, 0, 0);
        __builtin_amdgcn_s_setprio(0);
    }
#undef STAGE

    // epilogue: 32x32 C/D layout col=lane&31, row=(reg&3)+8*(reg>>2)+4*(lane>>5)
    const float wmean = *meanp;  // clamped mean|w| == 1/scale_w
#pragma unroll
    for (int m = 0; m < 4; ++m) {
#pragma unroll
        for (int r = 0; r < 16; ++r) {
            const int row = bm + wm + m * 32 + (r & 3) + 8 * (r >> 2) + 4 * lh;
            const float scale = rs[row] * wmean;
            float* orow = out + (size_t)row * N_OUT + bn + wn + l31;
#pragma unroll
            for (int n = 0; n < 4; ++n)
                orow[n * 32] = (float)accv[m][n][r] * scale;
        }
    }
}

extern "C" void kernel_launch(void* const* d_in, const int* in_sizes, int n_in,
                              void* d_out, int out_size, void* d_ws, size_t ws_size,
                              hipStream_t stream) {
    const float* x = (const float*)d_in[0];
    const float* w = (const float*)d_in[1];
    float* out = (float*)d_out;
    char* ws = (char*)d_ws;
    int8_t* q = (int8_t*)ws;
    int8_t* tw = (int8_t*)(ws + 33554432);
    float* rs = (float*)(ws + 50331648);
    double* partial = (double*)(ws + 50364416);
    float* meanp = (float*)(ws + 50372608);

    hipLaunchKernelGGL(quant_act, dim3(M_TOK / 4), dim3(256), 0, stream, x, q, rs);
    hipLaunchKernelGGL(wabs_sum, dim3(1024), dim3(256), 0, stream, w, partial);
    hipLaunchKernelGGL(ternarize, dim3((N_OUT * (size_t)K_DIM / 16) / 256), dim3(256), 0, stream, w, tw, partial, meanp);
    hipLaunchKernelGGL(gemm_i8, dim3(N_OUT / 256, M_TOK / 256), dim3(256), 0, stream, q, tw, rs, meanp, out);
}